// Round 11
// baseline (124.625 us; speedup 1.0000x reference)
//
#include <hip/hip_runtime.h>

// UniformBottomUpHTMM: T=64 trees, depth 10 (N1=2047 heap), C=16, M=64,
// G=16. r22: wave-autonomous quarter-trees (decorrelate the waves).
// r21 post-mortem: amdgpu_waves_per_eu(5) is a MINIMUM -- compiler over-
// squeezed to VGPR=48, re-spilling 44MB; 61us. Reverted to the proven
// launch_bounds(256,1)+fences codegen (VGPR 108, zero spill, 56us).
// r19 cycle budget: VALU-busy ~15.5us, LDS-issue ~15-25us, rest stall --
// but the two pipes can overlap; they don't because all 4 waves are
// PHASE-LOCKED: __syncthreads after L8/L7 re-aligns them, fence-delimited
// load bursts pile onto the LDS pipe together, and waves 1-3 idle through
// wave0's 7-level serial tail.
// Fix: the tree decomposes -- wave w owns L8[64w..64w+64) -> L7[32w..)
// -> ... -> one L2 node. Each wave runs leaf->L2 with NO __syncthreads
// (wave-internal lgkmcnt+wave_barrier only) on disjoint buffer columns;
// one __syncthreads; wave0 finishes L1+L0 (3 matvecs). Deletes 2 block
// syncs, lets waves drift (one wave's lgkm-wait overlaps another's VALU),
// and parallelizes the tail 4x. Matvec/fences/LDS layout (32KB, r21 diet)
// unchanged. Tripwire: WRITE_SIZE >> 4KB or VGPR far from ~108 => revert.
// Structure: 1024 independent blocks, one (t,g) each, no workspace/atomics.

#define C_DIM 16
#define M_DIM 64
#define G_DIM 16
#define T_TREES 64
#define N1 2047
#define NBLOCKS (T_TREES * G_DIM)   // 1024
#define BTS 20                      // padded row stride (floats) for xv-tables

__device__ __forceinline__ float4 f4add(float4 a, float4 b) {
    return make_float4(a.x + b.x, a.y + b.y, a.z + b.z, a.w + b.w);
}
__device__ __forceinline__ float4 f4mul(float4 a, float4 b) {
    return make_float4(a.x * b.x, a.y * b.y, a.z * b.z, a.w * b.w);
}
__device__ __forceinline__ float4 f4fma(float4 a, float4 b, float4 c) {
    return make_float4(fmaf(a.x, b.x, c.x), fmaf(a.y, b.y, c.y),
                       fmaf(a.z, b.z, c.z), fmaf(a.w, b.w, c.w));
}
__device__ __forceinline__ float hsum4(float4 a) { return a.x + a.y + a.z + a.w; }

// bp[q] = (A[4q+r]·s) * Bt[4q+r]; returns nu = sum(bp).
// Two 8-row halves with a hard sched fence between (r19-proven: caps
// in-flight ds_read_b128 liveness; VGPR 108).
__device__ __forceinline__ float matvec_bt(const float* __restrict__ A,
                                           const float* __restrict__ bt,
                                           const float4 sv[4], float4 bp[4])
{
    float nu = 0.f;
    #pragma unroll
    for (int h = 0; h < 2; ++h) {
        #pragma unroll
        for (int q = 2 * h; q < 2 * h + 2; ++q) {
            const float4 b4 = *(const float4*)(bt + 4 * q);
            float tr[4];
            #pragma unroll
            for (int r = 0; r < 4; ++r) {
                const float4* ar = (const float4*)(A + (4 * q + r) * 16);
                float4 m = f4mul(ar[0], sv[0]);
                m = f4fma(ar[1], sv[1], m);
                m = f4fma(ar[2], sv[2], m);
                m = f4fma(ar[3], sv[3], m);
                tr[r] = hsum4(m);
            }
            bp[q] = f4mul(make_float4(tr[0], tr[1], tr[2], tr[3]), b4);
            nu += hsum4(bp[q]);
        }
        __builtin_amdgcn_sched_barrier(0);   // liveness fence: half-matvec
    }
    return nu;
}

__global__ __launch_bounds__(256, 1) void htmm_fused(
    const int* __restrict__ x,
    const int* __restrict__ inv_map,
    const float* __restrict__ lA,
    const float* __restrict__ lB,
    const float* __restrict__ lPi,
    float* __restrict__ out)
{
    const int bid = blockIdx.x;           // 1024 blocks: g = bid>>6, t = bid&63
    const int tid = threadIdx.x;
    const int g = bid >> 6;
    const int t = bid & (T_TREES - 1);
    const int wv   = tid >> 6;            // wave 0..3 owns quarter-tree wv
    const int lane = tid & 63;

    // ---- manual LDS layout (r21 diet): 32768 B ----
    __shared__ __align__(16) unsigned char smem[32768];
    float* const sA   = (float*)(smem);            //     0 .. 1024   A row-major
    float* const sBt  = (float*)(smem + 1024);     //  1024 .. 6144   Bt[xv][c] stride 20
    float* const sPB  = (float*)(smem + 6144);     //  6144 .. 11264  leaf tables (dead after leaf)
    float* const sLog = (float*)(smem + 11264);    // 11264 .. 11520  (dead after leaf)
    float* const sPi  = (float*)(smem + 11520);    // 11520 .. 11584  (dead after tables)
    float* const buf1 = (float*)(smem + 6144);     // UNION: live from L7 on (8192B)
    unsigned char* const xs = smem + 14336;        // 14336 .. 16384
    float* const buf0 = (float*)(smem + 16384);    // 16384 .. 32768
    float* const wsum = (float*)(smem + 32752);    // buf0 row15 col252-255 (tail-unused)

    // ---- tree symbols (coalesced; 16 same-tree blocks share L2) ----
    {
        const int base = t * N1;
        for (int i = tid; i < N1; i += 256)
            xs[i] = (unsigned char)x[inv_map[base + i]];
    }
    // ---- A softmax (over i within 16-lane segments) ----
    {
        int j = tid >> 4, i = tid & 15;
        float v = lA[(i * C_DIM + j) * G_DIM + g];
        float mx = v;
        #pragma unroll
        for (int m = 1; m < 16; m <<= 1) mx = fmaxf(mx, __shfl_xor(mx, m, 16));
        float e = __expf(v - mx);
        float s = e;
        #pragma unroll
        for (int m = 1; m < 16; m <<= 1) s += __shfl_xor(s, m, 16);
        sA[i * C_DIM + j] = e / s;
    }
    // ---- B softmax (over m), written TRANSPOSED: sBt[xv*BTS + c] ----
    {
        int c = tid >> 4, l16 = tid & 15;
        float e0 = lB[(c * M_DIM + l16 +  0) * G_DIM + g];
        float e1 = lB[(c * M_DIM + l16 + 16) * G_DIM + g];
        float e2 = lB[(c * M_DIM + l16 + 32) * G_DIM + g];
        float e3 = lB[(c * M_DIM + l16 + 48) * G_DIM + g];
        float mx = fmaxf(fmaxf(e0, e1), fmaxf(e2, e3));
        #pragma unroll
        for (int m = 1; m < 16; m <<= 1) mx = fmaxf(mx, __shfl_xor(mx, m, 16));
        e0 = __expf(e0 - mx); e1 = __expf(e1 - mx);
        e2 = __expf(e2 - mx); e3 = __expf(e3 - mx);
        float s = e0 + e1 + e2 + e3;
        #pragma unroll
        for (int m = 1; m < 16; m <<= 1) s += __shfl_xor(s, m, 16);
        float inv = 1.f / s;
        sBt[(l16 +  0) * BTS + c] = e0 * inv;
        sBt[(l16 + 16) * BTS + c] = e1 * inv;
        sBt[(l16 + 32) * BTS + c] = e2 * inv;
        sBt[(l16 + 48) * BTS + c] = e3 * inv;
    }
    if (tid < C_DIM) {  // Pi softmax
        float v = lPi[tid * G_DIM + g];
        float mx = v;
        #pragma unroll
        for (int m = 1; m < 16; m <<= 1) mx = fmaxf(mx, __shfl_xor(mx, m, 16));
        float e = __expf(v - mx);
        float s = e;
        #pragma unroll
        for (int m = 1; m < 16; m <<= 1) s += __shfl_xor(s, m, 16);
        sPi[tid] = e / s;
    }
    __syncthreads();

    // ---- leaf tables: PB[xv][k] = 0.5*Pi[k]*Bt[xv][k]/nu, logNu[xv] ----
    if (tid < M_DIM) {
        const int xv = tid;
        float pb[16]; float nu = 0.f;
        #pragma unroll
        for (int k = 0; k < 16; ++k) {
            pb[k] = sPi[k] * sBt[xv * BTS + k];
            nu += pb[k];
        }
        const float inv = 0.5f / nu;
        #pragma unroll
        for (int k = 0; k < 16; ++k) sPB[xv * BTS + k] = pb[k] * inv;
        sLog[xv] = __logf(nu);
    }
    __syncthreads();

    float ll = 0.f;

    // ==== from here: NO __syncthreads until the cross-wave top ====
    // Wave wv owns L8 cols [64wv,64wv+64) -> L7 [32wv,+32) -> ... -> L2 {wv}.

    // ---- fused leaves (table) + L9 + L8: one L8 node per thread ----
    {
        const int idx = tid;
        const int p8  = 255 + idx;
        float4 s8v[4];
        #pragma unroll
        for (int q = 0; q < 4; ++q) s8v[q] = make_float4(0.f, 0.f, 0.f, 0.f);

        #pragma unroll
        for (int c9 = 0; c9 < 2; ++c9) {
            const int p9 = 2 * p8 + 1 + c9;
            const int xl = xs[2 * p9 + 1], xr = xs[2 * p9 + 2];
            const float* pl = &sPB[xl * BTS];
            const float* pr = &sPB[xr * BTS];
            float4 s9v[4];
            #pragma unroll
            for (int q = 0; q < 4; ++q)
                s9v[q] = f4add(*(const float4*)(pl + 4*q), *(const float4*)(pr + 4*q));
            ll += sLog[xl] + sLog[xr];

            const int xv = xs[p9];
            float4 bp[4];
            float nu = matvec_bt(sA, &sBt[xv * BTS], s9v, bp);
            ll += __logf(nu);
            const float inv = 0.5f / nu;
            const float4 iv = make_float4(inv, inv, inv, inv);
            #pragma unroll
            for (int q = 0; q < 4; ++q) s8v[q] = f4fma(bp[q], iv, s8v[q]);
            __builtin_amdgcn_sched_barrier(0);   // liveness fence: subtree done
        }
        const int xv = xs[p8];
        float4 bp[4];
        float nu = matvec_bt(sA, &sBt[xv * BTS], s8v, bp);
        ll += __logf(nu);
        const float inv = 1.f / nu;
        #pragma unroll
        for (int q = 0; q < 4; ++q) {
            buf0[(4*q + 0) * 256 + idx] = bp[q].x * inv;
            buf0[(4*q + 1) * 256 + idx] = bp[q].y * inv;
            buf0[(4*q + 2) * 256 + idx] = bp[q].z * inv;
            buf0[(4*q + 3) * 256 + idx] = bp[q].w * inv;
        }
    }
    asm volatile("s_waitcnt lgkmcnt(0)" ::: "memory");
    __builtin_amdgcn_wave_barrier();     // wave-local: own L8 slice complete

    // ---- L7: 32 nodes per wave (lanes 0-31) ----
    {
        if (lane < 32) {
            const int idx = 32 * wv + lane;
            float4 sv[4];
            #pragma unroll
            for (int q = 0; q < 4; ++q) {
                float2 c0 = *(const float2*)(&buf0[(4*q + 0) * 256 + 2 * idx]);
                float2 c1 = *(const float2*)(&buf0[(4*q + 1) * 256 + 2 * idx]);
                float2 c2 = *(const float2*)(&buf0[(4*q + 2) * 256 + 2 * idx]);
                float2 c3 = *(const float2*)(&buf0[(4*q + 3) * 256 + 2 * idx]);
                sv[q] = make_float4(0.5f * (c0.x + c0.y), 0.5f * (c1.x + c1.y),
                                    0.5f * (c2.x + c2.y), 0.5f * (c3.x + c3.y));
            }
            const int xv = xs[127 + idx];
            float4 bp[4];
            float nu = matvec_bt(sA, &sBt[xv * BTS], sv, bp);
            ll += __logf(nu);
            const float inv = 1.f / nu;
            #pragma unroll
            for (int q = 0; q < 4; ++q) {
                buf1[(4*q + 0) * 128 + idx] = bp[q].x * inv;
                buf1[(4*q + 1) * 128 + idx] = bp[q].y * inv;
                buf1[(4*q + 2) * 128 + idx] = bp[q].z * inv;
                buf1[(4*q + 3) * 128 + idx] = bp[q].w * inv;
            }
        }
        asm volatile("s_waitcnt lgkmcnt(0)" ::: "memory");
        __builtin_amdgcn_wave_barrier();
    }

    // ---- L6..L2 (16..1 nodes per wave): still no block sync ----
    float* cur = buf1; int cs = 128;
    float* nxt = buf0; int ns = 256;
    for (int cnt2 = 64; cnt2 >= 4; cnt2 >>= 1) {
        const int c = cnt2 >> 2;              // nodes per wave this level
        if (lane < c) {
            const int idx = c * wv + lane;
            float4 sv[4];
            #pragma unroll
            for (int q = 0; q < 4; ++q) {
                float2 c0 = *(const float2*)(&cur[(4*q + 0) * cs + 2 * idx]);
                float2 c1 = *(const float2*)(&cur[(4*q + 1) * cs + 2 * idx]);
                float2 c2 = *(const float2*)(&cur[(4*q + 2) * cs + 2 * idx]);
                float2 c3 = *(const float2*)(&cur[(4*q + 3) * cs + 2 * idx]);
                sv[q] = make_float4(0.5f * (c0.x + c0.y), 0.5f * (c1.x + c1.y),
                                    0.5f * (c2.x + c2.y), 0.5f * (c3.x + c3.y));
            }
            const int xv = xs[cnt2 - 1 + idx];
            float4 bp[4];
            float nu = matvec_bt(sA, &sBt[xv * BTS], sv, bp);
            ll += __logf(nu);
            const float inv = 1.f / nu;
            #pragma unroll
            for (int q = 0; q < 4; ++q) {
                nxt[(4*q + 0) * ns + idx] = bp[q].x * inv;
                nxt[(4*q + 1) * ns + idx] = bp[q].y * inv;
                nxt[(4*q + 2) * ns + idx] = bp[q].z * inv;
                nxt[(4*q + 3) * ns + idx] = bp[q].w * inv;
            }
        }
        asm volatile("s_waitcnt lgkmcnt(0)" ::: "memory");
        __builtin_amdgcn_wave_barrier();
        float* tp = cur; cur = nxt; nxt = tp;
        int ts = cs; cs = ns; ns = ts;
    }
    // post-loop (5 iters): cur = buf0 (cs=256), nxt = buf1 (ns=128)

    __syncthreads();   // cross-wave: all four L2 nodes (buf0 cols 0-3) ready

    // ---- L1 (2 nodes) + L0 (root): wave 0 only ----
    if (wv == 0) {
        for (int cnt2 = 2; cnt2 >= 1; cnt2 >>= 1) {
            if (lane < cnt2) {
                const int idx = lane;
                float4 sv[4];
                #pragma unroll
                for (int q = 0; q < 4; ++q) {
                    float2 c0 = *(const float2*)(&cur[(4*q + 0) * cs + 2 * idx]);
                    float2 c1 = *(const float2*)(&cur[(4*q + 1) * cs + 2 * idx]);
                    float2 c2 = *(const float2*)(&cur[(4*q + 2) * cs + 2 * idx]);
                    float2 c3 = *(const float2*)(&cur[(4*q + 3) * cs + 2 * idx]);
                    sv[q] = make_float4(0.5f * (c0.x + c0.y), 0.5f * (c1.x + c1.y),
                                        0.5f * (c2.x + c2.y), 0.5f * (c3.x + c3.y));
                }
                const int xv = xs[cnt2 - 1 + idx];
                float4 bp[4];
                float nu = matvec_bt(sA, &sBt[xv * BTS], sv, bp);
                ll += __logf(nu);
                const float inv = 1.f / nu;
                #pragma unroll
                for (int q = 0; q < 4; ++q) {
                    nxt[(4*q + 0) * ns + idx] = bp[q].x * inv;
                    nxt[(4*q + 1) * ns + idx] = bp[q].y * inv;
                    nxt[(4*q + 2) * ns + idx] = bp[q].z * inv;
                    nxt[(4*q + 3) * ns + idx] = bp[q].w * inv;
                }
            }
            asm volatile("s_waitcnt lgkmcnt(0)" ::: "memory");
            __builtin_amdgcn_wave_barrier();
            float* tp = cur; cur = nxt; nxt = tp;
            int ts = cs; cs = ns; ns = ts;
        }
    }

    // ---- reduce ll across block (wsum in buf0 row15 cols252-255) ----
    float v = ll;
    #pragma unroll
    for (int off = 32; off > 0; off >>= 1) v += __shfl_down(v, off, 64);
    if ((tid & 63) == 0) wsum[tid >> 6] = v;
    __syncthreads();
    if (tid == 0) out[t * G_DIM + g] = wsum[0] + wsum[1] + wsum[2] + wsum[3];
}

extern "C" void kernel_launch(void* const* d_in, const int* in_sizes, int n_in,
                              void* d_out, int out_size, void* d_ws, size_t ws_size,
                              hipStream_t stream) {
    const int*   x       = (const int*)d_in[0];
    const int*   inv_map = (const int*)d_in[6];
    const float* lA      = (const float*)d_in[7];
    const float* lB      = (const float*)d_in[8];
    const float* lPi     = (const float*)d_in[9];
    float* out = (float*)d_out;

    htmm_fused<<<dim3(NBLOCKS), dim3(256), 0, stream>>>(
        x, inv_map, lA, lB, lPi, out);
}

// Round 12
// 115.805 us; speedup vs baseline: 1.0762x; 1.0762x over previous
//
#include <hip/hip_runtime.h>

// UniformBottomUpHTMM: T=64 trees, depth 10 (N1=2047 heap), C=16, M=64,
// G=16. r23: LINEARITY — collapse all 512 L9 matvecs per block.
// r22 post-mortem: wave-autonomous quarters raised VALUBusy 27.6->45.8%
// at equal wall (redundant per-wave issue; wave0's dependent chain still
// 11 stages). Reverted to r19 phase structure (champion, 56us).
// New: tA[x] = A·PB[x] precomputed per block (64 matvecs, folded into
// the table phase, in-place over sPB). Then for an L9 node:
//   A·(PB[xl]+PB[xr]) = tA[xl]+tA[xr]   (linearity)
// so each L9 node = 8 b128 gathers + 16 adds + Bt-hadamard (~50 VALU /
// 12 LDS) instead of a full matvec (~340 VALU / 68 LDS). That removes
// HALF of all per-block matvecs (512 of 1023). L8+ can't collapse (nu
// normalization between levels is nonlinear). Matches the reference's
// own order (per-child matvec, then sum).
// Everything else = r19: fenced row-major matvec (VGPR 108 proven),
// launch_bounds(256,1) (cap>=demand, zero spill), r21 32KB LDS diet.
// Tripwires: WRITE_SIZE >> 4KB (spill) or VGPR > ~130 => revert/fence.
// Structure: 1024 independent blocks, one (t,g) each, no workspace/atomics.

#define C_DIM 16
#define M_DIM 64
#define G_DIM 16
#define T_TREES 64
#define N1 2047
#define NBLOCKS (T_TREES * G_DIM)   // 1024
#define BTS 20                      // padded row stride (floats) for xv-tables

__device__ __forceinline__ float4 f4add(float4 a, float4 b) {
    return make_float4(a.x + b.x, a.y + b.y, a.z + b.z, a.w + b.w);
}
__device__ __forceinline__ float4 f4mul(float4 a, float4 b) {
    return make_float4(a.x * b.x, a.y * b.y, a.z * b.z, a.w * b.w);
}
__device__ __forceinline__ float4 f4fma(float4 a, float4 b, float4 c) {
    return make_float4(fmaf(a.x, b.x, c.x), fmaf(a.y, b.y, c.y),
                       fmaf(a.z, b.z, c.z), fmaf(a.w, b.w, c.w));
}
__device__ __forceinline__ float hsum4(float4 a) { return a.x + a.y + a.z + a.w; }

// bp[q] = (A[4q+r]·s) * Bt[4q+r]; returns nu = sum(bp).
// Two 8-row halves with a hard sched fence between (r19-proven: caps
// in-flight ds_read_b128 liveness; VGPR 108).
__device__ __forceinline__ float matvec_bt(const float* __restrict__ A,
                                           const float* __restrict__ bt,
                                           const float4 sv[4], float4 bp[4])
{
    float nu = 0.f;
    #pragma unroll
    for (int h = 0; h < 2; ++h) {
        #pragma unroll
        for (int q = 2 * h; q < 2 * h + 2; ++q) {
            const float4 b4 = *(const float4*)(bt + 4 * q);
            float tr[4];
            #pragma unroll
            for (int r = 0; r < 4; ++r) {
                const float4* ar = (const float4*)(A + (4 * q + r) * 16);
                float4 m = f4mul(ar[0], sv[0]);
                m = f4fma(ar[1], sv[1], m);
                m = f4fma(ar[2], sv[2], m);
                m = f4fma(ar[3], sv[3], m);
                tr[r] = hsum4(m);
            }
            bp[q] = f4mul(make_float4(tr[0], tr[1], tr[2], tr[3]), b4);
            nu += hsum4(bp[q]);
        }
        __builtin_amdgcn_sched_barrier(0);   // liveness fence: half-matvec
    }
    return nu;
}

__global__ __launch_bounds__(256, 1) void htmm_fused(
    const int* __restrict__ x,
    const int* __restrict__ inv_map,
    const float* __restrict__ lA,
    const float* __restrict__ lB,
    const float* __restrict__ lPi,
    float* __restrict__ out)
{
    const int bid = blockIdx.x;           // 1024 blocks: g = bid>>6, t = bid&63
    const int tid = threadIdx.x;
    const int g = bid >> 6;
    const int t = bid & (T_TREES - 1);

    // ---- manual LDS layout (r21 diet): 32768 B ----
    __shared__ __align__(16) unsigned char smem[32768];
    float* const sA   = (float*)(smem);            //     0 .. 1024   A row-major
    float* const sBt  = (float*)(smem + 1024);     //  1024 .. 6144   Bt[xv][c] stride 20
    float* const sPB  = (float*)(smem + 6144);     //  6144 .. 11264  tA[x]=A·PB[x] (leaf-phase only)
    float* const sLog = (float*)(smem + 11264);    // 11264 .. 11520  (dead after leaf)
    float* const sPi  = (float*)(smem + 11520);    // 11520 .. 11584  (dead after tables)
    float* const buf1 = (float*)(smem + 6144);     // UNION: live from L7 on (8192B)
    unsigned char* const xs = smem + 14336;        // 14336 .. 16384
    float* const buf0 = (float*)(smem + 16384);    // 16384 .. 32768
    float* const wsum = (float*)(smem + 32752);    // buf0 row15 col252-255 (tail-unused)

    // ---- tree symbols (coalesced; 16 same-tree blocks share L2) ----
    {
        const int base = t * N1;
        for (int i = tid; i < N1; i += 256)
            xs[i] = (unsigned char)x[inv_map[base + i]];
    }
    // ---- A softmax (over i within 16-lane segments) ----
    {
        int j = tid >> 4, i = tid & 15;
        float v = lA[(i * C_DIM + j) * G_DIM + g];
        float mx = v;
        #pragma unroll
        for (int m = 1; m < 16; m <<= 1) mx = fmaxf(mx, __shfl_xor(mx, m, 16));
        float e = __expf(v - mx);
        float s = e;
        #pragma unroll
        for (int m = 1; m < 16; m <<= 1) s += __shfl_xor(s, m, 16);
        sA[i * C_DIM + j] = e / s;
    }
    // ---- B softmax (over m), written TRANSPOSED: sBt[xv*BTS + c] ----
    {
        int c = tid >> 4, l16 = tid & 15;
        float e0 = lB[(c * M_DIM + l16 +  0) * G_DIM + g];
        float e1 = lB[(c * M_DIM + l16 + 16) * G_DIM + g];
        float e2 = lB[(c * M_DIM + l16 + 32) * G_DIM + g];
        float e3 = lB[(c * M_DIM + l16 + 48) * G_DIM + g];
        float mx = fmaxf(fmaxf(e0, e1), fmaxf(e2, e3));
        #pragma unroll
        for (int m = 1; m < 16; m <<= 1) mx = fmaxf(mx, __shfl_xor(mx, m, 16));
        e0 = __expf(e0 - mx); e1 = __expf(e1 - mx);
        e2 = __expf(e2 - mx); e3 = __expf(e3 - mx);
        float s = e0 + e1 + e2 + e3;
        #pragma unroll
        for (int m = 1; m < 16; m <<= 1) s += __shfl_xor(s, m, 16);
        float inv = 1.f / s;
        sBt[(l16 +  0) * BTS + c] = e0 * inv;
        sBt[(l16 + 16) * BTS + c] = e1 * inv;
        sBt[(l16 + 32) * BTS + c] = e2 * inv;
        sBt[(l16 + 48) * BTS + c] = e3 * inv;
    }
    if (tid < C_DIM) {  // Pi softmax
        float v = lPi[tid * G_DIM + g];
        float mx = v;
        #pragma unroll
        for (int m = 1; m < 16; m <<= 1) mx = fmaxf(mx, __shfl_xor(mx, m, 16));
        float e = __expf(v - mx);
        float s = e;
        #pragma unroll
        for (int m = 1; m < 16; m <<= 1) s += __shfl_xor(s, m, 16);
        sPi[tid] = e / s;
    }
    __syncthreads();

    // ---- leaf tables + LINEARITY fold: write tA[x] = A·PB[x] ----
    // PB[x][k] = 0.5*Pi[k]*Bt[x][k]/nu stays in registers; only tA and
    // logNu are consumed downstream.
    if (tid < M_DIM) {
        const int xv = tid;
        float pb[16]; float nu = 0.f;
        #pragma unroll
        for (int k = 0; k < 16; ++k) {
            pb[k] = sPi[k] * sBt[xv * BTS + k];
            nu += pb[k];
        }
        const float inv = 0.5f / nu;
        #pragma unroll
        for (int k = 0; k < 16; ++k) pb[k] *= inv;
        sLog[xv] = __logf(nu);
        const float4 pv0 = make_float4(pb[0],  pb[1],  pb[2],  pb[3]);
        const float4 pv1 = make_float4(pb[4],  pb[5],  pb[6],  pb[7]);
        const float4 pv2 = make_float4(pb[8],  pb[9],  pb[10], pb[11]);
        const float4 pv3 = make_float4(pb[12], pb[13], pb[14], pb[15]);
        float ta[16];
        #pragma unroll
        for (int i = 0; i < 16; ++i) {
            const float4* ar = (const float4*)(sA + i * 16);
            float4 m = f4mul(ar[0], pv0);
            m = f4fma(ar[1], pv1, m);
            m = f4fma(ar[2], pv2, m);
            m = f4fma(ar[3], pv3, m);
            ta[i] = hsum4(m);
            if ((i & 3) == 3) __builtin_amdgcn_sched_barrier(0);  // cap in-flight
        }
        #pragma unroll
        for (int q = 0; q < 4; ++q)
            *(float4*)(&sPB[xv * BTS + 4 * q]) =
                make_float4(ta[4*q], ta[4*q+1], ta[4*q+2], ta[4*q+3]);
    }
    __syncthreads();

    float ll = 0.f;

    // ---- fused leaves+L9 (TABLE: tA[xl]+tA[xr]) + L8 matvec ----
    {
        const int idx = tid;
        const int p8  = 255 + idx;
        float4 s8v[4];
        #pragma unroll
        for (int q = 0; q < 4; ++q) s8v[q] = make_float4(0.f, 0.f, 0.f, 0.f);

        #pragma unroll
        for (int c9 = 0; c9 < 2; ++c9) {
            const int p9 = 2 * p8 + 1 + c9;
            const int xl = xs[2 * p9 + 1], xr = xs[2 * p9 + 2];
            const int xv = xs[p9];
            const float* tl = &sPB[xl * BTS];   // tA rows
            const float* tr = &sPB[xr * BTS];
            const float* bt = &sBt[xv * BTS];
            float4 bp[4]; float nu = 0.f;
            #pragma unroll
            for (int q = 0; q < 4; ++q) {
                float4 tv = f4add(*(const float4*)(tl + 4*q),
                                  *(const float4*)(tr + 4*q));
                bp[q] = f4mul(tv, *(const float4*)(bt + 4*q));
                nu += hsum4(bp[q]);
            }
            ll += sLog[xl] + sLog[xr] + __logf(nu);
            const float inv = 0.5f / nu;
            const float4 iv = make_float4(inv, inv, inv, inv);
            #pragma unroll
            for (int q = 0; q < 4; ++q) s8v[q] = f4fma(bp[q], iv, s8v[q]);
            __builtin_amdgcn_sched_barrier(0);   // liveness fence: subtree done
        }
        const int xv = xs[p8];
        float4 bp[4];
        float nu = matvec_bt(sA, &sBt[xv * BTS], s8v, bp);
        ll += __logf(nu);
        const float inv = 1.f / nu;
        #pragma unroll
        for (int q = 0; q < 4; ++q) {
            buf0[(4*q + 0) * 256 + idx] = bp[q].x * inv;
            buf0[(4*q + 1) * 256 + idx] = bp[q].y * inv;
            buf0[(4*q + 2) * 256 + idx] = bp[q].z * inv;
            buf0[(4*q + 3) * 256 + idx] = bp[q].w * inv;
        }
    }
    __syncthreads();

    // ---- L7: 128 nodes (buf1 aliases the now-dead tA region) ----
    if (tid < 128) {
        const int idx = tid;
        float4 sv[4];
        #pragma unroll
        for (int q = 0; q < 4; ++q) {
            float2 c0 = *(const float2*)(&buf0[(4*q + 0) * 256 + 2 * idx]);
            float2 c1 = *(const float2*)(&buf0[(4*q + 1) * 256 + 2 * idx]);
            float2 c2 = *(const float2*)(&buf0[(4*q + 2) * 256 + 2 * idx]);
            float2 c3 = *(const float2*)(&buf0[(4*q + 3) * 256 + 2 * idx]);
            sv[q] = make_float4(0.5f * (c0.x + c0.y), 0.5f * (c1.x + c1.y),
                                0.5f * (c2.x + c2.y), 0.5f * (c3.x + c3.y));
        }
        const int xv = xs[127 + idx];
        float4 bp[4];
        float nu = matvec_bt(sA, &sBt[xv * BTS], sv, bp);
        ll += __logf(nu);
        const float inv = 1.f / nu;
        #pragma unroll
        for (int q = 0; q < 4; ++q) {
            buf1[(4*q + 0) * 128 + idx] = bp[q].x * inv;
            buf1[(4*q + 1) * 128 + idx] = bp[q].y * inv;
            buf1[(4*q + 2) * 128 + idx] = bp[q].z * inv;
            buf1[(4*q + 3) * 128 + idx] = bp[q].w * inv;
        }
    }
    __syncthreads();

    // ---- L6..L0 (64..1 nodes): wave 0 only, LDS fences not barriers ----
    if (tid < 64) {
        float* cur = buf1; int cs = 128;
        float* nxt = buf0; int ns = 256;
        for (int cnt2 = 64; cnt2 >= 1; cnt2 >>= 1) {
            if (tid < cnt2) {
                const int idx = tid;
                float4 sv[4];
                #pragma unroll
                for (int q = 0; q < 4; ++q) {
                    float2 c0 = *(const float2*)(&cur[(4*q + 0) * cs + 2 * idx]);
                    float2 c1 = *(const float2*)(&cur[(4*q + 1) * cs + 2 * idx]);
                    float2 c2 = *(const float2*)(&cur[(4*q + 2) * cs + 2 * idx]);
                    float2 c3 = *(const float2*)(&cur[(4*q + 3) * cs + 2 * idx]);
                    sv[q] = make_float4(0.5f * (c0.x + c0.y), 0.5f * (c1.x + c1.y),
                                        0.5f * (c2.x + c2.y), 0.5f * (c3.x + c3.y));
                }
                const int xv = xs[cnt2 - 1 + idx];
                float4 bp[4];
                float nu = matvec_bt(sA, &sBt[xv * BTS], sv, bp);
                ll += __logf(nu);
                const float inv = 1.f / nu;
                #pragma unroll
                for (int q = 0; q < 4; ++q) {
                    nxt[(4*q + 0) * ns + idx] = bp[q].x * inv;
                    nxt[(4*q + 1) * ns + idx] = bp[q].y * inv;
                    nxt[(4*q + 2) * ns + idx] = bp[q].z * inv;
                    nxt[(4*q + 3) * ns + idx] = bp[q].w * inv;
                }
            }
            asm volatile("s_waitcnt lgkmcnt(0)" ::: "memory");
            __builtin_amdgcn_wave_barrier();
            float* tp = cur; cur = nxt; nxt = tp;
            int ts = cs; cs = ns; ns = ts;
        }
    }

    // ---- reduce ll across block (wsum in buf0 row15 cols252-255) ----
    float v = ll;
    #pragma unroll
    for (int off = 32; off > 0; off >>= 1) v += __shfl_down(v, off, 64);
    if ((tid & 63) == 0) wsum[tid >> 6] = v;
    __syncthreads();
    if (tid == 0) out[t * G_DIM + g] = wsum[0] + wsum[1] + wsum[2] + wsum[3];
}

extern "C" void kernel_launch(void* const* d_in, const int* in_sizes, int n_in,
                              void* d_out, int out_size, void* d_ws, size_t ws_size,
                              hipStream_t stream) {
    const int*   x       = (const int*)d_in[0];
    const int*   inv_map = (const int*)d_in[6];
    const float* lA      = (const float*)d_in[7];
    const float* lB      = (const float*)d_in[8];
    const float* lPi     = (const float*)d_in[9];
    float* out = (float*)d_out;

    htmm_fused<<<dim3(NBLOCKS), dim3(256), 0, stream>>>(
        x, inv_map, lA, lB, lPi, out);
}